// Round 17
// baseline (159.895 us; speedup 1.0000x reference)
//
#include <hip/hip_runtime.h>

// ---------------------------------------------------------------------------
// WAM_13056700579937: out = softmax_ax1(softmax_ax2((X X^T) W^T)) @ X + X
// B=16, C=512, HW=4096. fp32 in/out; internal bf16 MFMA (16x16x32).
//
// Round 17: gemm_out Bdswrite hoisted before compute (ds_write drains under
// MFMA; same barrier/race structure, ledger re-derived); static dbuf indices
// via #pragma unroll 2 in gsym/gemm_s.
// ---------------------------------------------------------------------------

typedef __attribute__((ext_vector_type(8))) short bf16x8;   // 8 bf16 = 4 VGPR
typedef __attribute__((ext_vector_type(4))) float f32x4;

#define DEVINL __device__ __forceinline__
#define CFENCE() asm volatile("" ::: "memory")

DEVINL unsigned short f2bf(float f) {   // RNE float->bf16 (finite inputs)
  union { float f; unsigned int u; } c; c.f = f;
  unsigned int u = c.u;
  u += 0x7fffu + ((u >> 16) & 1u);
  return (unsigned short)(u >> 16);
}

DEVINL float bf2f(unsigned short h) {
  union { unsigned int u; float f; } c; c.u = ((unsigned int)h) << 16;
  return c.f;
}

DEVINL void gld_lds16(const unsigned short* g, unsigned short* l) {
  __builtin_amdgcn_global_load_lds(
      (const __attribute__((address_space(1))) unsigned int*)g,
      (__attribute__((address_space(3))) unsigned int*)l,
      16 /*bytes, literal*/, 0, 0);
}

template<int N> DEVINL void vm_wait() {
  if constexpr (N == 0)       asm volatile("s_waitcnt vmcnt(0)" ::: "memory");
  else if constexpr (N == 2)  asm volatile("s_waitcnt vmcnt(2)" ::: "memory");
  else if constexpr (N == 4)  asm volatile("s_waitcnt vmcnt(4)" ::: "memory");
  else if constexpr (N == 6)  asm volatile("s_waitcnt vmcnt(6)" ::: "memory");
  else static_assert(N < 0, "unsupported vmcnt");
}

DEVINL void lgkm0() { asm volatile("s_waitcnt lgkmcnt(0)" ::: "memory"); }

DEVINL void sym_tile_decode(int t, int& tm, int& tn) {  // t in [0,10) -> upper 4x4
  if (t < 4)      { tm = 0; tn = t; }
  else if (t < 7) { tm = 1; tn = t - 3; }
  else if (t < 9) { tm = 2; tn = t - 5; }
  else            { tm = 3; tn = 3; }
}

// Batch-pinned XCD decode (bijective for grid = 16 * nper; lin&7 == XCD id).
DEVINL void xcd_batch_decode(int lin, int nper, int& batch, int& tile) {
  const int xcd  = lin & 7;
  const int slot = lin >> 3;          // [0, 2*nper)
  const int half = (slot >= nper) ? 1 : 0;
  batch = xcd * 2 + half;
  tile  = slot - half * nper;
}

// ---------------------------------------------------------------------------
// cvt fp32 -> bf16, x (8388608 f4) and W (65536 f4) in one launch.
// ---------------------------------------------------------------------------
__global__ __launch_bounds__(256)
void cvt2_kernel(const float* __restrict__ x, unsigned short* __restrict__ x_bf,
                 const float* __restrict__ Wm, unsigned short* __restrict__ W_bf) {
  long long i = (long long)blockIdx.x * 256 + threadIdx.x;
  const long long stride = (long long)gridDim.x * 256;
  for (; i < 8454144; i += stride) {
    const bool isX = (i < 8388608);
    const long long j = isX ? i : (i - 8388608);
    float4 v = isX ? ((const float4*)x)[j] : ((const float4*)Wm)[j];
    unsigned int lo = (unsigned int)f2bf(v.x) | ((unsigned int)f2bf(v.y) << 16);
    unsigned int hi = (unsigned int)f2bf(v.z) | ((unsigned int)f2bf(v.w) << 16);
    uint2 o; o.x = lo; o.y = hi;
    if (isX) ((uint2*)x_bf)[j] = o;
    else     ((uint2*)W_bf)[j] = o;
  }
}

// ---------------------------------------------------------------------------
// G = X X^T, symmetric + split-K, 2-deep counted-vmcnt pipeline. 128^2 tiles.
// 1D grid 640 with batch-pinned XCD swizzle. Partials written BF16.
// ---------------------------------------------------------------------------
__global__ __launch_bounds__(256)
void gemm_gsym(const unsigned short* __restrict__ X, unsigned short* __restrict__ P) {
  constexpr int HALF = 128 * 32;           // shorts per buffer (8 KB)
  __shared__ unsigned short As[2 * HALF];
  __shared__ unsigned short Bs[2 * HALF];
  const int tid = threadIdx.x;
  const int l   = tid & 63;
  const int w   = tid >> 6;
  const int wr  = w >> 1, wc = w & 1;
  int b, tile; xcd_batch_decode(blockIdx.x, 40, b, tile);
  const int t   = tile >> 2;
  const int split = tile & 3;
  int tm, tn; sym_tile_decode(t, tm, tn);

  const unsigned short* Ab = X + (long long)b * 2097152 + (long long)(tm * 128) * 4096;
  const unsigned short* Bb = X + (long long)b * 2097152 + (long long)(tn * 128) * 4096;

  f32x4 acc[4][4];
  #pragma unroll
  for (int m = 0; m < 4; ++m)
    #pragma unroll
    for (int n = 0; n < 4; ++n) acc[m][n] = (f32x4){0.f, 0.f, 0.f, 0.f};

  const int srow = tid >> 2;
  const int scol = ((tid & 3) ^ ((tid >> 3) & 3)) * 8;
  const int ch8  = (((l >> 4) ^ ((l >> 1) & 3)) * 8);

  auto stage = [&](int buf, int k0) {
    #pragma unroll
    for (int i = 0; i < 2; ++i)
      gld_lds16(Ab + (long long)(i * 64 + srow) * 4096 + k0 + scol, &As[buf * HALF + i * 2048 + tid * 8]);
    #pragma unroll
    for (int i = 0; i < 2; ++i)
      gld_lds16(Bb + (long long)(i * 64 + srow) * 4096 + k0 + scol, &Bs[buf * HALF + i * 2048 + tid * 8]);
  };
  auto compute = [&](int buf) {
    bf16x8 af[4], bfr[4];
    #pragma unroll
    for (int m = 0; m < 4; ++m)
      af[m] = *(const bf16x8*)&As[buf * HALF + (wr * 64 + m * 16 + (l & 15)) * 32 + ch8];
    #pragma unroll
    for (int n = 0; n < 4; ++n)
      bfr[n] = *(const bf16x8*)&Bs[buf * HALF + (wc * 64 + n * 16 + (l & 15)) * 32 + ch8];
    __builtin_amdgcn_s_setprio(1);
    #pragma unroll
    for (int m = 0; m < 4; ++m)
      #pragma unroll
      for (int n = 0; n < 4; ++n)
        acc[m][n] = __builtin_amdgcn_mfma_f32_16x16x32_bf16(af[m], bfr[n], acc[m][n], 0, 0, 0);
    __builtin_amdgcn_s_setprio(0);
  };

  const int k_beg = split * 1024;
  constexpr int NK = 32;
  stage(0, k_beg);
  stage(1, k_beg + 32);
  int ks = k_beg + 64;
  #pragma unroll 2
  for (int k = 0; k < NK - 2; ++k) {
    vm_wait<4>();
    CFENCE(); __builtin_amdgcn_s_barrier(); CFENCE();
    compute(k & 1);
    CFENCE(); __builtin_amdgcn_s_barrier(); CFENCE();
    stage(k & 1, ks); ks += 32;
  }
  vm_wait<4>();
  CFENCE(); __builtin_amdgcn_s_barrier(); CFENCE();
  compute((NK - 2) & 1);
  vm_wait<0>();
  CFENCE(); __builtin_amdgcn_s_barrier(); CFENCE();
  compute((NK - 1) & 1);

  unsigned short* Pt = P + (((long long)b * 10 + t) * 4 + split) * 16384;
  const int cc = l & 15, r4 = (l >> 4) * 4;
  #pragma unroll
  for (int m = 0; m < 4; ++m) {
    #pragma unroll
    for (int n = 0; n < 4; ++n) {
      const int row = wr * 64 + m * 16 + r4;
      const int col = wc * 64 + n * 16 + cc;
      #pragma unroll
      for (int j = 0; j < 4; ++j)
        Pt[(row + j) * 128 + col] = f2bf(acc[m][n][j]);
    }
  }
}

// ---------------------------------------------------------------------------
// Reduce 4 bf16 split-K partials (fp32 sum) -> bf16 G tile; mirror off-diag.
// ---------------------------------------------------------------------------
__global__ __launch_bounds__(256)
void reduce_mirror(const unsigned short* __restrict__ P, unsigned short* __restrict__ G) {
  __shared__ unsigned short T[128 * 129];
  const int tid = threadIdx.x;
  const int b = blockIdx.y;
  const int t = blockIdx.x;
  int tm, tn; sym_tile_decode(t, tm, tn);
  const unsigned short* Pt = P + ((long long)(b * 10 + t) * 4) * 16384;
  unsigned short* Gb = G + (long long)b * 262144;

  #pragma unroll
  for (int e = 0; e < 16; ++e) {
    const int v = e * 256 + tid;            // ushort4 index (4 elems/thread)
    ushort4 s0 = ((const ushort4*)Pt)[v];
    ushort4 s1 = ((const ushort4*)(Pt + 16384))[v];
    ushort4 s2 = ((const ushort4*)(Pt + 32768))[v];
    ushort4 s3 = ((const ushort4*)(Pt + 49152))[v];
    unsigned int h0 = f2bf(bf2f(s0.x) + bf2f(s1.x) + bf2f(s2.x) + bf2f(s3.x));
    unsigned int h1 = f2bf(bf2f(s0.y) + bf2f(s1.y) + bf2f(s2.y) + bf2f(s3.y));
    unsigned int h2 = f2bf(bf2f(s0.z) + bf2f(s1.z) + bf2f(s2.z) + bf2f(s3.z));
    unsigned int h3 = f2bf(bf2f(s0.w) + bf2f(s1.w) + bf2f(s2.w) + bf2f(s3.w));
    const int idx = v * 4;
    const int r = idx >> 7, c = idx & 127;
    unsigned int* gp = (unsigned int*)(Gb + (long long)(tm * 128 + r) * 512 + tn * 128 + c);
    gp[0] = h0 | (h1 << 16);
    gp[1] = h2 | (h3 << 16);
    unsigned short* tp = &T[r * 129 + c];
    tp[0] = (unsigned short)h0; tp[1] = (unsigned short)h1;
    tp[2] = (unsigned short)h2; tp[3] = (unsigned short)h3;
  }
  if (tm != tn) {
    __syncthreads();
    #pragma unroll
    for (int e = 0; e < 16; ++e) {
      const int idx = (e * 256 + tid) * 4;
      const int r = idx >> 7, c = idx & 127;
      unsigned int o0 = T[(c + 0) * 129 + r], o1 = T[(c + 1) * 129 + r];
      unsigned int o2 = T[(c + 2) * 129 + r], o3 = T[(c + 3) * 129 + r];
      unsigned int* gp = (unsigned int*)(Gb + (long long)(tn * 128 + r) * 512 + tm * 128 + c);
      gp[0] = o0 | (o1 << 16);
      gp[1] = o2 | (o3 << 16);
    }
  }
}

// ---------------------------------------------------------------------------
// s-gemm + row-LSE partials: C = A * B^T (s[c][d]), 64^2 tiles.
// stats[b][c][tn] = (m, l) per 64-col block (float2).
// ---------------------------------------------------------------------------
__global__ __launch_bounds__(256)
void gemm_s(const unsigned short* __restrict__ A, const unsigned short* __restrict__ B,
            float* __restrict__ C, float* __restrict__ stats) {
  constexpr int HALF = 64 * 32;
  __shared__ unsigned short As[2 * HALF];
  __shared__ unsigned short Bs[2 * HALF];
  __shared__ float sm[2][64], sl[2][64];

  const int tid = threadIdx.x;
  const int l   = tid & 63;
  const int w   = tid >> 6;
  const int wr  = w >> 1, wc = w & 1;
  const int bz  = blockIdx.y;
  const int tm  = blockIdx.x >> 3;
  const int tn  = blockIdx.x & 7;

  const unsigned short* Ab = A + (long long)bz * 262144 + (long long)(tm * 64) * 512;
  const unsigned short* Bb = B + (long long)(tn * 64) * 512;

  f32x4 acc[2][2];
  #pragma unroll
  for (int m = 0; m < 2; ++m)
    #pragma unroll
    for (int n = 0; n < 2; ++n) acc[m][n] = (f32x4){0.f, 0.f, 0.f, 0.f};

  const int srow = tid >> 2;
  const int scol = ((tid & 3) ^ ((tid >> 3) & 3)) * 8;
  const int ch8  = (((l >> 4) ^ ((l >> 1) & 3)) * 8);

  auto stage = [&](int buf, int k0) {
    gld_lds16(Ab + (long long)srow * 512 + k0 + scol, &As[buf * HALF + tid * 8]);
    gld_lds16(Bb + (long long)srow * 512 + k0 + scol, &Bs[buf * HALF + tid * 8]);
  };
  auto compute = [&](int buf) {
    bf16x8 af[2], bfr[2];
    #pragma unroll
    for (int m = 0; m < 2; ++m)
      af[m] = *(const bf16x8*)&As[buf * HALF + (wr * 32 + m * 16 + (l & 15)) * 32 + ch8];
    #pragma unroll
    for (int n = 0; n < 2; ++n)
      bfr[n] = *(const bf16x8*)&Bs[buf * HALF + (wc * 32 + n * 16 + (l & 15)) * 32 + ch8];
    __builtin_amdgcn_s_setprio(1);
    #pragma unroll
    for (int m = 0; m < 2; ++m)
      #pragma unroll
      for (int n = 0; n < 2; ++n)
        acc[m][n] = __builtin_amdgcn_mfma_f32_16x16x32_bf16(af[m], bfr[n], acc[m][n], 0, 0, 0);
    __builtin_amdgcn_s_setprio(0);
  };

  stage(0, 0);
  stage(1, 32);
  int ks = 64;
  #pragma unroll 2
  for (int k = 0; k < 14; ++k) {
    vm_wait<2>();
    CFENCE(); __builtin_amdgcn_s_barrier(); CFENCE();
    compute(k & 1);
    CFENCE(); __builtin_amdgcn_s_barrier(); CFENCE();
    stage(k & 1, ks); ks += 32;
  }
  vm_wait<2>();
  CFENCE(); __builtin_amdgcn_s_barrier(); CFENCE();
  compute(0);
  vm_wait<0>();
  CFENCE(); __builtin_amdgcn_s_barrier(); CFENCE();
  compute(1);

  const int cc = l & 15, r4 = (l >> 4) * 4;
  const int row0 = tm * 64 + wr * 32;
  const int col0 = tn * 64 + wc * 32;
  #pragma unroll
  for (int m = 0; m < 2; ++m) {
    #pragma unroll
    for (int n = 0; n < 2; ++n) {
      const int row = row0 + m * 16 + r4;
      const int col = col0 + n * 16 + cc;
      long long base = (long long)bz * 262144 + (long long)row * 512 + col;
      #pragma unroll
      for (int j = 0; j < 4; ++j)
        C[base + (long long)j * 512] = acc[m][n][j];
    }
  }

  // --- row-LSE partial epilogue ---
  float mv[2][4], lv[2][4];
  #pragma unroll
  for (int m = 0; m < 2; ++m)
    #pragma unroll
    for (int j = 0; j < 4; ++j) {
      float v0 = acc[m][0][j], v1 = acc[m][1][j];
      float mx = fmaxf(v0, v1);
      mv[m][j] = mx;
      lv[m][j] = __expf(v0 - mx) + __expf(v1 - mx);
    }
  #pragma unroll
  for (int off = 1; off < 16; off <<= 1) {
    #pragma unroll
    for (int m = 0; m < 2; ++m)
      #pragma unroll
      for (int j = 0; j < 4; ++j) {
        float om = __shfl_xor(mv[m][j], off);
        float ol = __shfl_xor(lv[m][j], off);
        float nm = fmaxf(mv[m][j], om);
        lv[m][j] = lv[m][j] * __expf(mv[m][j] - nm) + ol * __expf(om - nm);
        mv[m][j] = nm;
      }
  }
  if ((l & 15) == 0) {
    const int g = l >> 4;
    #pragma unroll
    for (int m = 0; m < 2; ++m)
      #pragma unroll
      for (int j = 0; j < 4; ++j) {
        const int r = wr * 32 + m * 16 + g * 4 + j;
        sm[wc][r] = mv[m][j];
        sl[wc][r] = lv[m][j];
      }
  }
  __syncthreads();
  if (tid < 64) {
    float m0 = sm[0][tid], l0 = sl[0][tid];
    float m1 = sm[1][tid], l1 = sl[1][tid];
    float M = fmaxf(m0, m1);
    float L = l0 * __expf(m0 - M) + l1 * __expf(m1 - M);
    float2 st; st.x = M; st.y = L;
    ((float2*)stats)[((long long)bz * 512 + tm * 64 + tid) * 8 + tn] = st;
  }
}

// ---------------------------------------------------------------------------
// col_softmax_v2: combine LSE partials -> lse[c]; one s_f pass computing
// t = exp(exp(s-lse)) kept in LDS bf16 while col-summing; write a = t/sum (+I).
// ---------------------------------------------------------------------------
__global__ __launch_bounds__(256)
void col_softmax_v2(const float* __restrict__ s, const float* __restrict__ stats,
                    unsigned short* __restrict__ a_bf) {
  __shared__ float lse[512];
  __shared__ unsigned short pt[512][32];
  __shared__ float cs[8][32];
  const int tid = threadIdx.x;
  const int b   = blockIdx.y;

  #pragma unroll
  for (int rr = 0; rr < 2; ++rr) {
    const int r = tid + rr * 256;
    const float2* pp = (const float2*)stats + ((long long)b * 512 + r) * 8;
    float M = pp[0].x;
    #pragma unroll
    for (int q = 1; q < 8; ++q) M = fmaxf(M, pp[q].x);
    float Z = 0.f;
    #pragma unroll
    for (int q = 0; q < 8; ++q) Z += pp[q].y * __expf(pp[q].x - M);
    lse[r] = M + __logf(Z);
  }
  __syncthreads();

  const int dl = tid & 31;
  const int st = tid >> 5;
  const int d  = blockIdx.x * 32 + dl;
  const float* sp = s + (long long)b * 262144 + d;
  float sum = 0.f;
  #pragma unroll 4
  for (int c = st * 64; c < st * 64 + 64; ++c) {
    float p = __expf(sp[(long long)c * 512] - lse[c]);
    float t = __expf(p);
    pt[c][dl] = f2bf(t);
    sum += t;
  }
  cs[st][dl] = sum;
  __syncthreads();
  if (st == 0) {
    float tot = ((cs[0][dl] + cs[1][dl]) + (cs[2][dl] + cs[3][dl]))
              + ((cs[4][dl] + cs[5][dl]) + (cs[6][dl] + cs[7][dl]));
    cs[0][dl] = 1.0f / tot;
  }
  __syncthreads();
  const float inv = cs[0][dl];
  unsigned short* q = a_bf + (long long)b * 262144 + d;
  #pragma unroll 4
  for (int c = st * 64; c < st * 64 + 64; ++c) {
    float v = bf2f(pt[c][dl]) * inv;
    if (c == d) v += 1.0f;               // residual fold: out = (a+I) @ X
    q[(long long)c * 512] = f2bf(v);
  }
}

// ---------------------------------------------------------------------------
// out-gemm with FUSED B-transpose. Race-safe schedule, Bdswrite pre-compute:
// per step: vm_wait<4> (own A(k)) -> BAR (all A(k) + Bs published) ->
// vm_wait<2> (B(k+1) regs) -> Bdswrite(other buf) -> compute(buf) ->
// lgkm0 -> BAR -> issue Bload(k+2)/Agload(k+2).
// ds_writes drain under MFMA; write target != compute source buffer; WAR
// separated by previous step's end barrier.
// ---------------------------------------------------------------------------
__global__ __launch_bounds__(256)
void gemm_out(const unsigned short* __restrict__ A, const unsigned short* __restrict__ X,
              float* __restrict__ C) {
  __shared__ unsigned short As[2][128 * 32];   // 16 KB
  __shared__ unsigned int   Bs[2][16][132];    // 16.5 KB

  const int tid = threadIdx.x;
  const int l   = tid & 63;
  const int w   = tid >> 6;
  const int wr  = w >> 1, wc = w & 1;
  const int bz  = blockIdx.y;
  const int tm  = blockIdx.x >> 5;    // 4 M-tiles (128 c)
  const int tn  = blockIdx.x & 31;    // 32 N-tiles (128 h)

  const unsigned short* Ab = A + (long long)bz * 262144  + (long long)(tm * 128) * 512;
  const unsigned short* Xb = X + (long long)bz * 2097152 + tn * 128;

  f32x4 acc[4][4];
  #pragma unroll
  for (int m = 0; m < 4; ++m)
    #pragma unroll
    for (int n = 0; n < 4; ++n) acc[m][n] = (f32x4){0.f, 0.f, 0.f, 0.f};

  const int srow = tid >> 2;
  const int scol = ((tid & 3) ^ ((tid >> 3) & 3)) * 8;
  const int ch8  = (((l >> 4) ^ ((l >> 1) & 3)) * 8);
  const int bp_  = tid >> 4;          // dpair 0..15
  const int bh_  = tid & 15;          // h-octet 0..15
  const unsigned short* Bsrc = Xb + (long long)(2 * bp_) * 4096 + bh_ * 8;

  auto Agload = [&](int buf, int k0) {
    #pragma unroll
    for (int i = 0; i < 2; ++i)
      gld_lds16(Ab + (long long)(i * 64 + srow) * 512 + k0 + scol, &As[buf][i * 2048 + tid * 8]);
  };
  auto Bload = [&](int k0, uint4& g0, uint4& g1) {
    g0 = *(const uint4*)(Bsrc + (long long)k0 * 4096);
    g1 = *(const uint4*)(Bsrc + (long long)(k0 + 1) * 4096);
  };
  auto Bdswrite = [&](int buf, const uint4& g0, const uint4& g1) {
    unsigned int w0 = (g0.x & 0xffffu) | (g1.x << 16);
    unsigned int w1 = (g0.x >> 16)    | (g1.x & 0xffff0000u);
    unsigned int w2 = (g0.y & 0xffffu) | (g1.y << 16);
    unsigned int w3 = (g0.y >> 16)    | (g1.y & 0xffff0000u);
    unsigned int w4 = (g0.z & 0xffffu) | (g1.z << 16);
    unsigned int w5 = (g0.z >> 16)    | (g1.z & 0xffff0000u);
    unsigned int w6 = (g0.w & 0xffffu) | (g1.w << 16);
    unsigned int w7 = (g0.w >> 16)    | (g1.w & 0xffff0000u);
    unsigned int* dst = &Bs[buf][bp_][bh_ * 8];
    uint4 o0; o0.x = w0; o0.y = w1; o0.z = w2; o0.w = w3;
    uint4 o1; o1.x = w4; o1.y = w5; o1.z = w6; o1.w = w7;
    *(uint4*)dst = o0;
    *(uint4*)(dst + 4) = o1;
  };
  auto compute = [&](int buf) {
    bf16x8 af[4], bfr[4];
    #pragma unroll
    for (int m = 0; m < 4; ++m)
      af[m] = *(const bf16x8*)&As[buf][(wr * 64 + m * 16 + (l & 15)) * 32 + ch8];
    const int hl = wc * 64 + (l & 15);
    const int p0 = (l >> 4) * 4;
    #pragma unroll
    for (int n = 0; n < 4; ++n) {
      unsigned int wv[4];
      #pragma unroll
      for (int i = 0; i < 4; ++i) wv[i] = Bs[buf][p0 + i][hl + n * 16];
      bfr[n] = *(bf16x8*)wv;
    }
    __builtin_amdgcn_s_setprio(1);
    #pragma unroll
    for (int m = 0; m < 4; ++m)
      #pragma unroll
      for (int n = 0; n < 4; ++n)
        acc[m][n] = __builtin_amdgcn_mfma_f32_16x16x32_bf16(af[m], bfr[n], acc[m][n], 0, 0, 0);
    __builtin_amdgcn_s_setprio(0);
  };

  // prologue: tiles 0 (buf0/e-regs) and 1 (buf1/o-regs)
  uint4 e0, e1, o0, o1;
  Bload(0, e0, e1);    // 2 VMEM
  Agload(0, 0);        // 2
  Bload(32, o0, o1);   // 2
  Agload(1, 32);       // 2
  vm_wait<6>();        // B(0) regs in
  Bdswrite(0, e0, e1);
  lgkm0();             // own Bs[0] writes done; published at first loop barrier

  // steady: 14 K-steps, unrolled x2 (static e/o reg sets)
  #pragma unroll 1
  for (int kk = 0; kk < 7; ++kk) {
    const int k = 2 * kk;
    // even: tile k (buf0); write B(k+1)->Bs[1] under compute; load tile k+2 (e)
    vm_wait<4>();                         // own A(k) retired
    CFENCE(); __builtin_amdgcn_s_barrier(); CFENCE();  // ALL A(k) landed + Bs pub
    vm_wait<2>();                         // B(k+1) regs in
    Bdswrite(1, o0, o1);                  // drains under compute
    compute(0);
    lgkm0();
    CFENCE(); __builtin_amdgcn_s_barrier(); CFENCE();  // Bs[1] published
    Bload((k + 2) * 32, e0, e1);
    Agload(0, (k + 2) * 32);
    // odd: tile k+1 (buf1); write B(k+2)->Bs[0] under compute; load tile k+3 (o)
    vm_wait<4>();                         // own A(k+1) retired
    CFENCE(); __builtin_amdgcn_s_barrier(); CFENCE();
    vm_wait<2>();                         // B(k+2) regs in
    Bdswrite(0, e0, e1);
    compute(1);
    lgkm0();
    CFENCE(); __builtin_amdgcn_s_barrier(); CFENCE();
    Bload((k + 3) * 32, o0, o1);
    Agload(1, (k + 3) * 32);
  }
  // epilogue: tiles 14, 15
  vm_wait<4>();                           // own A(14) retired
  CFENCE(); __builtin_amdgcn_s_barrier(); CFENCE();
  vm_wait<2>();                           // B(15) regs in
  Bdswrite(1, o0, o1);
  compute(0);
  vm_wait<0>();                           // A(15) retired
  lgkm0();
  CFENCE(); __builtin_amdgcn_s_barrier(); CFENCE();
  compute(1);

  const int cc = l & 15, r4 = (l >> 4) * 4;
  const int row0 = tm * 128 + wr * 64;
  const int col0 = tn * 128 + wc * 64;
  #pragma unroll
  for (int m = 0; m < 4; ++m) {
    #pragma unroll
    for (int n = 0; n < 4; ++n) {
      const int row = row0 + m * 16 + r4;
      const int col = col0 + n * 16 + cc;
      long long base = (long long)bz * 2097152 + (long long)row * 4096 + col;
      #pragma unroll
      for (int j = 0; j < 4; ++j)
        __builtin_nontemporal_store(acc[m][n][j], &C[base + (long long)j * 4096]);
    }
  }
}

// ---------------------------------------------------------------------------
extern "C" void kernel_launch(void* const* d_in, const int* in_sizes, int n_in,
                              void* d_out, int out_size, void* d_ws, size_t ws_size,
                              hipStream_t stream) {
  (void)in_sizes; (void)n_in; (void)out_size; (void)ws_size;
  const float* x = (const float*)d_in[0];   // [16][512][4096]
  const float* W = (const float*)d_in[1];   // [512][512]
  float* out = (float*)d_out;               // [16][512][4096] = 128 MiB
  char* ws = (char*)d_ws;

  // d_out scratch (dead before final gemm overwrites it):
  unsigned short* P = (unsigned short*)((char*)d_out + 67108864); // [64,84 MiB) bf16 splitK partials
  float* s_stats    = (float*)((char*)d_out + 67108864);          // reuses P space (P dead after reduce_mirror)

  // ws layout (88.5 MiB high water, known-safe):
  unsigned short* x_bf = (unsigned short*)ws;                 // [0, 64 MiB)
  unsigned short* G_bf = (unsigned short*)(ws + 67108864);    // 8 MiB
  float*          s_f  = (float*)(ws + 75497472);             // 16 MiB
  unsigned short* W_bf = (unsigned short*)(ws + 92274688);    // 0.5 MiB
  unsigned short* a_bf = G_bf;   // aliases G_bf (dead after s-gemm)

  // 1) cvt x -> x_bf and W -> W_bf (single streaming launch)
  cvt2_kernel<<<4096, 256, 0, stream>>>(x, x_bf, W, W_bf);

  // 2) G = X X^T: symmetric tiles x 4 K-splits, batch-pinned XCD swizzle
  gemm_gsym<<<640, 256, 0, stream>>>(x_bf, P);

  // 3) reduce partials (fp32 sum), write bf16 G (+ mirrored transpose)
  reduce_mirror<<<dim3(10, 16), 256, 0, stream>>>(P, G_bf);

  // 4) s = G W^T (f32) + per-row LSE partials (row-softmax fused)
  gemm_s<<<dim3(64, 16), 256, 0, stream>>>(G_bf, W_bf, s_f, s_stats);

  // 5) col_softmax_v2: LSE combine + p + col-softmax + identity fold -> a
  col_softmax_v2<<<dim3(16, 16), 256, 0, stream>>>(s_f, s_stats, a_bf);

  // 6) out = (a+I) @ X with fused B-transpose (reads x_bf directly)
  gemm_out<<<dim3(128, 16), 256, 0, stream>>>(a_bf, x_bf, out);
}

// Round 18
// 158.569 us; speedup vs baseline: 1.0084x; 1.0084x over previous
//
#include <hip/hip_runtime.h>

// ---------------------------------------------------------------------------
// WAM_13056700579937: out = softmax_ax1(softmax_ax2((X X^T) W^T)) @ X + X
// B=16, C=512, HW=4096. fp32 in/out; internal bf16 MFMA (16x16x32).
//
// FINAL (round-16 config): race-safe 2-deep counted-vmcnt pipelines;
// x read once (cvt only); xT eliminated (transpose fused into out-gemm
// B-staging); residual folded into a (+I); row-softmax fused into s-gemm
// (LSE partials); col-softmax single-pass; symmetric+split-K G with bf16
// partials; batch-pinned XCD swizzle on gsym.
// ---------------------------------------------------------------------------

typedef __attribute__((ext_vector_type(8))) short bf16x8;   // 8 bf16 = 4 VGPR
typedef __attribute__((ext_vector_type(4))) float f32x4;

#define DEVINL __device__ __forceinline__
#define CFENCE() asm volatile("" ::: "memory")

DEVINL unsigned short f2bf(float f) {   // RNE float->bf16 (finite inputs)
  union { float f; unsigned int u; } c; c.f = f;
  unsigned int u = c.u;
  u += 0x7fffu + ((u >> 16) & 1u);
  return (unsigned short)(u >> 16);
}

DEVINL float bf2f(unsigned short h) {
  union { unsigned int u; float f; } c; c.u = ((unsigned int)h) << 16;
  return c.f;
}

DEVINL void gld_lds16(const unsigned short* g, unsigned short* l) {
  __builtin_amdgcn_global_load_lds(
      (const __attribute__((address_space(1))) unsigned int*)g,
      (__attribute__((address_space(3))) unsigned int*)l,
      16 /*bytes, literal*/, 0, 0);
}

template<int N> DEVINL void vm_wait() {
  if constexpr (N == 0)       asm volatile("s_waitcnt vmcnt(0)" ::: "memory");
  else if constexpr (N == 2)  asm volatile("s_waitcnt vmcnt(2)" ::: "memory");
  else if constexpr (N == 4)  asm volatile("s_waitcnt vmcnt(4)" ::: "memory");
  else if constexpr (N == 6)  asm volatile("s_waitcnt vmcnt(6)" ::: "memory");
  else static_assert(N < 0, "unsupported vmcnt");
}

DEVINL void lgkm0() { asm volatile("s_waitcnt lgkmcnt(0)" ::: "memory"); }

DEVINL void sym_tile_decode(int t, int& tm, int& tn) {  // t in [0,10) -> upper 4x4
  if (t < 4)      { tm = 0; tn = t; }
  else if (t < 7) { tm = 1; tn = t - 3; }
  else if (t < 9) { tm = 2; tn = t - 5; }
  else            { tm = 3; tn = 3; }
}

// Batch-pinned XCD decode (bijective for grid = 16 * nper; lin&7 == XCD id).
DEVINL void xcd_batch_decode(int lin, int nper, int& batch, int& tile) {
  const int xcd  = lin & 7;
  const int slot = lin >> 3;          // [0, 2*nper)
  const int half = (slot >= nper) ? 1 : 0;
  batch = xcd * 2 + half;
  tile  = slot - half * nper;
}

// ---------------------------------------------------------------------------
// cvt fp32 -> bf16, x (8388608 f4) and W (65536 f4) in one launch.
// ---------------------------------------------------------------------------
__global__ __launch_bounds__(256)
void cvt2_kernel(const float* __restrict__ x, unsigned short* __restrict__ x_bf,
                 const float* __restrict__ Wm, unsigned short* __restrict__ W_bf) {
  long long i = (long long)blockIdx.x * 256 + threadIdx.x;
  const long long stride = (long long)gridDim.x * 256;
  for (; i < 8454144; i += stride) {
    const bool isX = (i < 8388608);
    const long long j = isX ? i : (i - 8388608);
    float4 v = isX ? ((const float4*)x)[j] : ((const float4*)Wm)[j];
    unsigned int lo = (unsigned int)f2bf(v.x) | ((unsigned int)f2bf(v.y) << 16);
    unsigned int hi = (unsigned int)f2bf(v.z) | ((unsigned int)f2bf(v.w) << 16);
    uint2 o; o.x = lo; o.y = hi;
    if (isX) ((uint2*)x_bf)[j] = o;
    else     ((uint2*)W_bf)[j] = o;
  }
}

// ---------------------------------------------------------------------------
// G = X X^T, symmetric + split-K, 2-deep counted-vmcnt pipeline. 128^2 tiles.
// 1D grid 640 with batch-pinned XCD swizzle. Partials written BF16.
// ---------------------------------------------------------------------------
__global__ __launch_bounds__(256)
void gemm_gsym(const unsigned short* __restrict__ X, unsigned short* __restrict__ P) {
  constexpr int HALF = 128 * 32;           // shorts per buffer (8 KB)
  __shared__ unsigned short As[2 * HALF];
  __shared__ unsigned short Bs[2 * HALF];
  const int tid = threadIdx.x;
  const int l   = tid & 63;
  const int w   = tid >> 6;
  const int wr  = w >> 1, wc = w & 1;
  int b, tile; xcd_batch_decode(blockIdx.x, 40, b, tile);
  const int t   = tile >> 2;
  const int split = tile & 3;
  int tm, tn; sym_tile_decode(t, tm, tn);

  const unsigned short* Ab = X + (long long)b * 2097152 + (long long)(tm * 128) * 4096;
  const unsigned short* Bb = X + (long long)b * 2097152 + (long long)(tn * 128) * 4096;

  f32x4 acc[4][4];
  #pragma unroll
  for (int m = 0; m < 4; ++m)
    #pragma unroll
    for (int n = 0; n < 4; ++n) acc[m][n] = (f32x4){0.f, 0.f, 0.f, 0.f};

  const int srow = tid >> 2;
  const int scol = ((tid & 3) ^ ((tid >> 3) & 3)) * 8;
  const int ch8  = (((l >> 4) ^ ((l >> 1) & 3)) * 8);

  auto stage = [&](int buf, int k0) {
    #pragma unroll
    for (int i = 0; i < 2; ++i)
      gld_lds16(Ab + (long long)(i * 64 + srow) * 4096 + k0 + scol, &As[buf * HALF + i * 2048 + tid * 8]);
    #pragma unroll
    for (int i = 0; i < 2; ++i)
      gld_lds16(Bb + (long long)(i * 64 + srow) * 4096 + k0 + scol, &Bs[buf * HALF + i * 2048 + tid * 8]);
  };
  auto compute = [&](int buf) {
    bf16x8 af[4], bfr[4];
    #pragma unroll
    for (int m = 0; m < 4; ++m)
      af[m] = *(const bf16x8*)&As[buf * HALF + (wr * 64 + m * 16 + (l & 15)) * 32 + ch8];
    #pragma unroll
    for (int n = 0; n < 4; ++n)
      bfr[n] = *(const bf16x8*)&Bs[buf * HALF + (wc * 64 + n * 16 + (l & 15)) * 32 + ch8];
    __builtin_amdgcn_s_setprio(1);
    #pragma unroll
    for (int m = 0; m < 4; ++m)
      #pragma unroll
      for (int n = 0; n < 4; ++n)
        acc[m][n] = __builtin_amdgcn_mfma_f32_16x16x32_bf16(af[m], bfr[n], acc[m][n], 0, 0, 0);
    __builtin_amdgcn_s_setprio(0);
  };

  const int k_beg = split * 1024;
  constexpr int NK = 32;
  stage(0, k_beg);
  stage(1, k_beg + 32);
  int ks = k_beg + 64;
  for (int k = 0; k < NK - 2; ++k) {
    vm_wait<4>();
    CFENCE(); __builtin_amdgcn_s_barrier(); CFENCE();
    compute(k & 1);
    CFENCE(); __builtin_amdgcn_s_barrier(); CFENCE();
    stage(k & 1, ks); ks += 32;
  }
  vm_wait<4>();
  CFENCE(); __builtin_amdgcn_s_barrier(); CFENCE();
  compute((NK - 2) & 1);
  vm_wait<0>();
  CFENCE(); __builtin_amdgcn_s_barrier(); CFENCE();
  compute((NK - 1) & 1);

  unsigned short* Pt = P + (((long long)b * 10 + t) * 4 + split) * 16384;
  const int cc = l & 15, r4 = (l >> 4) * 4;
  #pragma unroll
  for (int m = 0; m < 4; ++m) {
    #pragma unroll
    for (int n = 0; n < 4; ++n) {
      const int row = wr * 64 + m * 16 + r4;
      const int col = wc * 64 + n * 16 + cc;
      #pragma unroll
      for (int j = 0; j < 4; ++j)
        Pt[(row + j) * 128 + col] = f2bf(acc[m][n][j]);
    }
  }
}

// ---------------------------------------------------------------------------
// Reduce 4 bf16 split-K partials (fp32 sum) -> bf16 G tile; mirror off-diag.
// ---------------------------------------------------------------------------
__global__ __launch_bounds__(256)
void reduce_mirror(const unsigned short* __restrict__ P, unsigned short* __restrict__ G) {
  __shared__ unsigned short T[128 * 129];
  const int tid = threadIdx.x;
  const int b = blockIdx.y;
  const int t = blockIdx.x;
  int tm, tn; sym_tile_decode(t, tm, tn);
  const unsigned short* Pt = P + ((long long)(b * 10 + t) * 4) * 16384;
  unsigned short* Gb = G + (long long)b * 262144;

  #pragma unroll
  for (int e = 0; e < 16; ++e) {
    const int v = e * 256 + tid;            // ushort4 index (4 elems/thread)
    ushort4 s0 = ((const ushort4*)Pt)[v];
    ushort4 s1 = ((const ushort4*)(Pt + 16384))[v];
    ushort4 s2 = ((const ushort4*)(Pt + 32768))[v];
    ushort4 s3 = ((const ushort4*)(Pt + 49152))[v];
    unsigned int h0 = f2bf(bf2f(s0.x) + bf2f(s1.x) + bf2f(s2.x) + bf2f(s3.x));
    unsigned int h1 = f2bf(bf2f(s0.y) + bf2f(s1.y) + bf2f(s2.y) + bf2f(s3.y));
    unsigned int h2 = f2bf(bf2f(s0.z) + bf2f(s1.z) + bf2f(s2.z) + bf2f(s3.z));
    unsigned int h3 = f2bf(bf2f(s0.w) + bf2f(s1.w) + bf2f(s2.w) + bf2f(s3.w));
    const int idx = v * 4;
    const int r = idx >> 7, c = idx & 127;
    unsigned int* gp = (unsigned int*)(Gb + (long long)(tm * 128 + r) * 512 + tn * 128 + c);
    gp[0] = h0 | (h1 << 16);
    gp[1] = h2 | (h3 << 16);
    unsigned short* tp = &T[r * 129 + c];
    tp[0] = (unsigned short)h0; tp[1] = (unsigned short)h1;
    tp[2] = (unsigned short)h2; tp[3] = (unsigned short)h3;
  }
  if (tm != tn) {
    __syncthreads();
    #pragma unroll
    for (int e = 0; e < 16; ++e) {
      const int idx = (e * 256 + tid) * 4;
      const int r = idx >> 7, c = idx & 127;
      unsigned int o0 = T[(c + 0) * 129 + r], o1 = T[(c + 1) * 129 + r];
      unsigned int o2 = T[(c + 2) * 129 + r], o3 = T[(c + 3) * 129 + r];
      unsigned int* gp = (unsigned int*)(Gb + (long long)(tn * 128 + r) * 512 + tm * 128 + c);
      gp[0] = o0 | (o1 << 16);
      gp[1] = o2 | (o3 << 16);
    }
  }
}

// ---------------------------------------------------------------------------
// s-gemm + row-LSE partials: C = A * B^T (s[c][d]), 64^2 tiles.
// stats[b][c][tn] = (m, l) per 64-col block (float2).
// ---------------------------------------------------------------------------
__global__ __launch_bounds__(256)
void gemm_s(const unsigned short* __restrict__ A, const unsigned short* __restrict__ B,
            float* __restrict__ C, float* __restrict__ stats) {
  constexpr int HALF = 64 * 32;
  __shared__ unsigned short As[2 * HALF];
  __shared__ unsigned short Bs[2 * HALF];
  __shared__ float sm[2][64], sl[2][64];

  const int tid = threadIdx.x;
  const int l   = tid & 63;
  const int w   = tid >> 6;
  const int wr  = w >> 1, wc = w & 1;
  const int bz  = blockIdx.y;
  const int tm  = blockIdx.x >> 3;
  const int tn  = blockIdx.x & 7;

  const unsigned short* Ab = A + (long long)bz * 262144 + (long long)(tm * 64) * 512;
  const unsigned short* Bb = B + (long long)(tn * 64) * 512;

  f32x4 acc[2][2];
  #pragma unroll
  for (int m = 0; m < 2; ++m)
    #pragma unroll
    for (int n = 0; n < 2; ++n) acc[m][n] = (f32x4){0.f, 0.f, 0.f, 0.f};

  const int srow = tid >> 2;
  const int scol = ((tid & 3) ^ ((tid >> 3) & 3)) * 8;
  const int ch8  = (((l >> 4) ^ ((l >> 1) & 3)) * 8);

  auto stage = [&](int buf, int k0) {
    gld_lds16(Ab + (long long)srow * 512 + k0 + scol, &As[buf * HALF + tid * 8]);
    gld_lds16(Bb + (long long)srow * 512 + k0 + scol, &Bs[buf * HALF + tid * 8]);
  };
  auto compute = [&](int buf) {
    bf16x8 af[2], bfr[2];
    #pragma unroll
    for (int m = 0; m < 2; ++m)
      af[m] = *(const bf16x8*)&As[buf * HALF + (wr * 32 + m * 16 + (l & 15)) * 32 + ch8];
    #pragma unroll
    for (int n = 0; n < 2; ++n)
      bfr[n] = *(const bf16x8*)&Bs[buf * HALF + (wc * 32 + n * 16 + (l & 15)) * 32 + ch8];
    __builtin_amdgcn_s_setprio(1);
    #pragma unroll
    for (int m = 0; m < 2; ++m)
      #pragma unroll
      for (int n = 0; n < 2; ++n)
        acc[m][n] = __builtin_amdgcn_mfma_f32_16x16x32_bf16(af[m], bfr[n], acc[m][n], 0, 0, 0);
    __builtin_amdgcn_s_setprio(0);
  };

  stage(0, 0);
  stage(1, 32);
  int ks = 64;
  for (int k = 0; k < 14; ++k) {
    vm_wait<2>();
    CFENCE(); __builtin_amdgcn_s_barrier(); CFENCE();
    compute(k & 1);
    CFENCE(); __builtin_amdgcn_s_barrier(); CFENCE();
    stage(k & 1, ks); ks += 32;
  }
  vm_wait<2>();
  CFENCE(); __builtin_amdgcn_s_barrier(); CFENCE();
  compute(0);
  vm_wait<0>();
  CFENCE(); __builtin_amdgcn_s_barrier(); CFENCE();
  compute(1);

  const int cc = l & 15, r4 = (l >> 4) * 4;
  const int row0 = tm * 64 + wr * 32;
  const int col0 = tn * 64 + wc * 32;
  #pragma unroll
  for (int m = 0; m < 2; ++m) {
    #pragma unroll
    for (int n = 0; n < 2; ++n) {
      const int row = row0 + m * 16 + r4;
      const int col = col0 + n * 16 + cc;
      long long base = (long long)bz * 262144 + (long long)row * 512 + col;
      #pragma unroll
      for (int j = 0; j < 4; ++j)
        C[base + (long long)j * 512] = acc[m][n][j];
    }
  }

  // --- row-LSE partial epilogue ---
  float mv[2][4], lv[2][4];
  #pragma unroll
  for (int m = 0; m < 2; ++m)
    #pragma unroll
    for (int j = 0; j < 4; ++j) {
      float v0 = acc[m][0][j], v1 = acc[m][1][j];
      float mx = fmaxf(v0, v1);
      mv[m][j] = mx;
      lv[m][j] = __expf(v0 - mx) + __expf(v1 - mx);
    }
  #pragma unroll
  for (int off = 1; off < 16; off <<= 1) {
    #pragma unroll
    for (int m = 0; m < 2; ++m)
      #pragma unroll
      for (int j = 0; j < 4; ++j) {
        float om = __shfl_xor(mv[m][j], off);
        float ol = __shfl_xor(lv[m][j], off);
        float nm = fmaxf(mv[m][j], om);
        lv[m][j] = lv[m][j] * __expf(mv[m][j] - nm) + ol * __expf(om - nm);
        mv[m][j] = nm;
      }
  }
  if ((l & 15) == 0) {
    const int g = l >> 4;
    #pragma unroll
    for (int m = 0; m < 2; ++m)
      #pragma unroll
      for (int j = 0; j < 4; ++j) {
        const int r = wr * 32 + m * 16 + g * 4 + j;
        sm[wc][r] = mv[m][j];
        sl[wc][r] = lv[m][j];
      }
  }
  __syncthreads();
  if (tid < 64) {
    float m0 = sm[0][tid], l0 = sl[0][tid];
    float m1 = sm[1][tid], l1 = sl[1][tid];
    float M = fmaxf(m0, m1);
    float L = l0 * __expf(m0 - M) + l1 * __expf(m1 - M);
    float2 st; st.x = M; st.y = L;
    ((float2*)stats)[((long long)bz * 512 + tm * 64 + tid) * 8 + tn] = st;
  }
}

// ---------------------------------------------------------------------------
// col_softmax_v2: combine LSE partials -> lse[c]; one s_f pass computing
// t = exp(exp(s-lse)) kept in LDS bf16 while col-summing; write a = t/sum (+I).
// ---------------------------------------------------------------------------
__global__ __launch_bounds__(256)
void col_softmax_v2(const float* __restrict__ s, const float* __restrict__ stats,
                    unsigned short* __restrict__ a_bf) {
  __shared__ float lse[512];
  __shared__ unsigned short pt[512][32];
  __shared__ float cs[8][32];
  const int tid = threadIdx.x;
  const int b   = blockIdx.y;

  #pragma unroll
  for (int rr = 0; rr < 2; ++rr) {
    const int r = tid + rr * 256;
    const float2* pp = (const float2*)stats + ((long long)b * 512 + r) * 8;
    float M = pp[0].x;
    #pragma unroll
    for (int q = 1; q < 8; ++q) M = fmaxf(M, pp[q].x);
    float Z = 0.f;
    #pragma unroll
    for (int q = 0; q < 8; ++q) Z += pp[q].y * __expf(pp[q].x - M);
    lse[r] = M + __logf(Z);
  }
  __syncthreads();

  const int dl = tid & 31;
  const int st = tid >> 5;
  const int d  = blockIdx.x * 32 + dl;
  const float* sp = s + (long long)b * 262144 + d;
  float sum = 0.f;
  #pragma unroll 4
  for (int c = st * 64; c < st * 64 + 64; ++c) {
    float p = __expf(sp[(long long)c * 512] - lse[c]);
    float t = __expf(p);
    pt[c][dl] = f2bf(t);
    sum += t;
  }
  cs[st][dl] = sum;
  __syncthreads();
  if (st == 0) {
    float tot = ((cs[0][dl] + cs[1][dl]) + (cs[2][dl] + cs[3][dl]))
              + ((cs[4][dl] + cs[5][dl]) + (cs[6][dl] + cs[7][dl]));
    cs[0][dl] = 1.0f / tot;
  }
  __syncthreads();
  const float inv = cs[0][dl];
  unsigned short* q = a_bf + (long long)b * 262144 + d;
  #pragma unroll 4
  for (int c = st * 64; c < st * 64 + 64; ++c) {
    float v = bf2f(pt[c][dl]) * inv;
    if (c == d) v += 1.0f;               // residual fold: out = (a+I) @ X
    q[(long long)c * 512] = f2bf(v);
  }
}

// ---------------------------------------------------------------------------
// out-gemm with FUSED B-transpose. Race-fixed schedule:
// per K-step: vm_wait<4> (own A(k)) -> s_barrier (ALL waves' A(k) landed,
// Bs published) -> compute -> vm_wait<2> -> Bdswrite(k+1) -> lgkm0 ->
// s_barrier -> issue Bload(k+2)/Agload(k+2).
// ---------------------------------------------------------------------------
__global__ __launch_bounds__(256)
void gemm_out(const unsigned short* __restrict__ A, const unsigned short* __restrict__ X,
              float* __restrict__ C) {
  __shared__ unsigned short As[2][128 * 32];   // 16 KB
  __shared__ unsigned int   Bs[2][16][132];    // 16.5 KB

  const int tid = threadIdx.x;
  const int l   = tid & 63;
  const int w   = tid >> 6;
  const int wr  = w >> 1, wc = w & 1;
  const int bz  = blockIdx.y;
  const int tm  = blockIdx.x >> 5;    // 4 M-tiles (128 c)
  const int tn  = blockIdx.x & 31;    // 32 N-tiles (128 h)

  const unsigned short* Ab = A + (long long)bz * 262144  + (long long)(tm * 128) * 512;
  const unsigned short* Xb = X + (long long)bz * 2097152 + tn * 128;

  f32x4 acc[4][4];
  #pragma unroll
  for (int m = 0; m < 4; ++m)
    #pragma unroll
    for (int n = 0; n < 4; ++n) acc[m][n] = (f32x4){0.f, 0.f, 0.f, 0.f};

  const int srow = tid >> 2;
  const int scol = ((tid & 3) ^ ((tid >> 3) & 3)) * 8;
  const int ch8  = (((l >> 4) ^ ((l >> 1) & 3)) * 8);
  const int bp_  = tid >> 4;          // dpair 0..15
  const int bh_  = tid & 15;          // h-octet 0..15
  const unsigned short* Bsrc = Xb + (long long)(2 * bp_) * 4096 + bh_ * 8;

  auto Agload = [&](int buf, int k0) {
    #pragma unroll
    for (int i = 0; i < 2; ++i)
      gld_lds16(Ab + (long long)(i * 64 + srow) * 512 + k0 + scol, &As[buf][i * 2048 + tid * 8]);
  };
  auto Bload = [&](int k0, uint4& g0, uint4& g1) {
    g0 = *(const uint4*)(Bsrc + (long long)k0 * 4096);
    g1 = *(const uint4*)(Bsrc + (long long)(k0 + 1) * 4096);
  };
  auto Bdswrite = [&](int buf, const uint4& g0, const uint4& g1) {
    unsigned int w0 = (g0.x & 0xffffu) | (g1.x << 16);
    unsigned int w1 = (g0.x >> 16)    | (g1.x & 0xffff0000u);
    unsigned int w2 = (g0.y & 0xffffu) | (g1.y << 16);
    unsigned int w3 = (g0.y >> 16)    | (g1.y & 0xffff0000u);
    unsigned int w4 = (g0.z & 0xffffu) | (g1.z << 16);
    unsigned int w5 = (g0.z >> 16)    | (g1.z & 0xffff0000u);
    unsigned int w6 = (g0.w & 0xffffu) | (g1.w << 16);
    unsigned int w7 = (g0.w >> 16)    | (g1.w & 0xffff0000u);
    unsigned int* dst = &Bs[buf][bp_][bh_ * 8];
    uint4 o0; o0.x = w0; o0.y = w1; o0.z = w2; o0.w = w3;
    uint4 o1; o1.x = w4; o1.y = w5; o1.z = w6; o1.w = w7;
    *(uint4*)dst = o0;
    *(uint4*)(dst + 4) = o1;
  };
  auto compute = [&](int buf) {
    bf16x8 af[4], bfr[4];
    #pragma unroll
    for (int m = 0; m < 4; ++m)
      af[m] = *(const bf16x8*)&As[buf][(wr * 64 + m * 16 + (l & 15)) * 32 + ch8];
    const int hl = wc * 64 + (l & 15);
    const int p0 = (l >> 4) * 4;
    #pragma unroll
    for (int n = 0; n < 4; ++n) {
      unsigned int wv[4];
      #pragma unroll
      for (int i = 0; i < 4; ++i) wv[i] = Bs[buf][p0 + i][hl + n * 16];
      bfr[n] = *(bf16x8*)wv;
    }
    __builtin_amdgcn_s_setprio(1);
    #pragma unroll
    for (int m = 0; m < 4; ++m)
      #pragma unroll
      for (int n = 0; n < 4; ++n)
        acc[m][n] = __builtin_amdgcn_mfma_f32_16x16x32_bf16(af[m], bfr[n], acc[m][n], 0, 0, 0);
    __builtin_amdgcn_s_setprio(0);
  };

  // prologue: tiles 0 (buf0/e-regs) and 1 (buf1/o-regs)
  uint4 e0, e1, o0, o1;
  Bload(0, e0, e1);    // 2 VMEM
  Agload(0, 0);        // 2
  Bload(32, o0, o1);   // 2
  Agload(1, 32);       // 2
  vm_wait<6>();        // B(0) regs in
  Bdswrite(0, e0, e1);
  lgkm0();             // own Bs[0] writes done; published at first loop barrier

  // steady: 14 K-steps, unrolled x2 (static e/o reg sets)
  #pragma unroll 1
  for (int kk = 0; kk < 7; ++kk) {
    const int k = 2 * kk;
    // even: tile k (buf0); write B(k+1) -> Bs[1]; load tile k+2 (e-regs)
    vm_wait<4>();                         // own A(k) retired
    CFENCE(); __builtin_amdgcn_s_barrier(); CFENCE();  // ALL A(k) landed + Bs pub
    compute(0);
    vm_wait<2>();                         // B(k+1) regs in
    Bdswrite(1, o0, o1);
    lgkm0();
    CFENCE(); __builtin_amdgcn_s_barrier(); CFENCE();  // all done reading bufs
    Bload((k + 2) * 32, e0, e1);
    Agload(0, (k + 2) * 32);
    // odd: tile k+1 (buf1); write B(k+2) -> Bs[0]; load tile k+3 (o-regs)
    vm_wait<4>();                         // own A(k+1) retired
    CFENCE(); __builtin_amdgcn_s_barrier(); CFENCE();
    compute(1);
    vm_wait<2>();
    Bdswrite(0, e0, e1);
    lgkm0();
    CFENCE(); __builtin_amdgcn_s_barrier(); CFENCE();
    Bload((k + 3) * 32, o0, o1);
    Agload(1, (k + 3) * 32);
  }
  // epilogue: tiles 14, 15
  vm_wait<4>();                           // own A(14) retired
  CFENCE(); __builtin_amdgcn_s_barrier(); CFENCE();
  compute(0);
  vm_wait<0>();                           // B(15) regs + A(15) retired
  Bdswrite(1, o0, o1);
  lgkm0();
  CFENCE(); __builtin_amdgcn_s_barrier(); CFENCE();
  compute(1);

  const int cc = l & 15, r4 = (l >> 4) * 4;
  const int row0 = tm * 128 + wr * 64;
  const int col0 = tn * 128 + wc * 64;
  #pragma unroll
  for (int m = 0; m < 4; ++m) {
    #pragma unroll
    for (int n = 0; n < 4; ++n) {
      const int row = row0 + m * 16 + r4;
      const int col = col0 + n * 16 + cc;
      long long base = (long long)bz * 2097152 + (long long)row * 4096 + col;
      #pragma unroll
      for (int j = 0; j < 4; ++j)
        __builtin_nontemporal_store(acc[m][n][j], &C[base + (long long)j * 4096]);
    }
  }
}

// ---------------------------------------------------------------------------
extern "C" void kernel_launch(void* const* d_in, const int* in_sizes, int n_in,
                              void* d_out, int out_size, void* d_ws, size_t ws_size,
                              hipStream_t stream) {
  (void)in_sizes; (void)n_in; (void)out_size; (void)ws_size;
  const float* x = (const float*)d_in[0];   // [16][512][4096]
  const float* W = (const float*)d_in[1];   // [512][512]
  float* out = (float*)d_out;               // [16][512][4096] = 128 MiB
  char* ws = (char*)d_ws;

  // d_out scratch (dead before final gemm overwrites it):
  unsigned short* P = (unsigned short*)((char*)d_out + 67108864); // [64,84 MiB) bf16 splitK partials
  float* s_stats    = (float*)((char*)d_out + 67108864);          // reuses P space (P dead after reduce_mirror)

  // ws layout (88.5 MiB high water, known-safe):
  unsigned short* x_bf = (unsigned short*)ws;                 // [0, 64 MiB)
  unsigned short* G_bf = (unsigned short*)(ws + 67108864);    // 8 MiB
  float*          s_f  = (float*)(ws + 75497472);             // 16 MiB
  unsigned short* W_bf = (unsigned short*)(ws + 92274688);    // 0.5 MiB
  unsigned short* a_bf = G_bf;   // aliases G_bf (dead after s-gemm)

  // 1) cvt x -> x_bf and W -> W_bf (single streaming launch)
  cvt2_kernel<<<4096, 256, 0, stream>>>(x, x_bf, W, W_bf);

  // 2) G = X X^T: symmetric tiles x 4 K-splits, batch-pinned XCD swizzle
  gemm_gsym<<<640, 256, 0, stream>>>(x_bf, P);

  // 3) reduce partials (fp32 sum), write bf16 G (+ mirrored transpose)
  reduce_mirror<<<dim3(10, 16), 256, 0, stream>>>(P, G_bf);

  // 4) s = G W^T (f32) + per-row LSE partials (row-softmax fused)
  gemm_s<<<dim3(64, 16), 256, 0, stream>>>(G_bf, W_bf, s_f, s_stats);

  // 5) col_softmax_v2: LSE combine + p + col-softmax + identity fold -> a
  col_softmax_v2<<<dim3(16, 16), 256, 0, stream>>>(s_f, s_stats, a_bf);

  // 6) out = (a+I) @ X with fused B-transpose (reads x_bf directly)
  gemm_out<<<dim3(128, 16), 256, 0, stream>>>(a_bf, x_bf, out);
}